// Round 9
// baseline (171.895 us; speedup 1.0000x reference)
//
#include <hip/hip_runtime.h>
#include <hip/hip_bf16.h>

typedef short bf16x8 __attribute__((ext_vector_type(8)));
typedef float f32x4 __attribute__((ext_vector_type(4)));

__device__ inline unsigned short f2bf(float f) {
    union { float f; unsigned u; } c; c.f = f;
    unsigned r = c.u + 0x7fffu + ((c.u >> 16) & 1u);
    return (unsigned short)(r >> 16);
}
__device__ inline float bf2f(unsigned short u) {
    union { unsigned u; float f; } c; c.u = ((unsigned)u) << 16; return c.f;
}
__device__ inline unsigned cvt_pk_bf16(float lo, float hi) {
    unsigned r;
    asm("v_cvt_pk_bf16_f32 %0, %1, %2" : "=v"(r) : "v"(lo), "v"(hi));
    return r;
}
__device__ inline float fast_exp2(float x) {
#if __has_builtin(__builtin_amdgcn_exp2f)
    return __builtin_amdgcn_exp2f(x);
#else
    return __exp2f(x);
#endif
}

// ---------- fp32 -> bf16 convert ----------
__global__ __launch_bounds__(256) void k_f32_to_bf16(const float* __restrict__ in,
                                                     unsigned short* __restrict__ out, int n4) {
    int i = blockIdx.x * 256 + threadIdx.x;
    if (i >= n4) return;
    f32x4 v = *(const f32x4*)&in[(size_t)i * 4];
    ushort4 o;
    o.x = f2bf(v[0]); o.y = f2bf(v[1]); o.z = f2bf(v[2]); o.w = f2bf(v[3]);
    *(ushort4*)&out[(size_t)i * 4] = o;
}

// ---------- transpose [K][N] fp32 -> [N][K] bf16 ----------
__global__ __launch_bounds__(256) void k_transpose_bf16(const float* __restrict__ in,
                                                        unsigned short* __restrict__ out,
                                                        int K, int N) {
    int idx = blockIdx.x * 256 + threadIdx.x;
    if (idx >= N * K) return;
    int n = idx / K, k = idx % K;
    out[idx] = f2bf(in[(size_t)k * N + n]);
}

// ---------- re-layout K and V into MFMA-fragment-coalesced tiles ----------
__global__ __launch_bounds__(256) void k_relayout(const unsigned short* __restrict__ qkv,
                                                  unsigned short* __restrict__ kt2,
                                                  unsigned short* __restrict__ vt2) {
    const int bh = blockIdx.y;
    const int b = bh >> 3, h = bh & 7;
    const int jt = blockIdx.x;
    const int t = threadIdx.x;
    __shared__ unsigned short tile[32][72];
    const int j = t >> 3, dc = (t & 7) * 8;
    const size_t qbase = (size_t)(b * 1024 + jt * 32 + j) * 1536;
    const size_t chunk = ((size_t)bh * 32 + jt) * 2048;
    bf16x8 kv = *(const bf16x8*)&qkv[qbase + 512 + h * 64 + dc];
    *(bf16x8*)&kt2[chunk + (dc >> 5) * 1024 + j * 32 + (dc & 31)] = kv;
    bf16x8 vv = *(const bf16x8*)&qkv[qbase + 1024 + h * 64 + dc];
    *(bf16x8*)&tile[j][dc] = vv;
    __syncthreads();
    const int d = t >> 2, j0 = (t & 3) * 8;
    union { bf16x8 v; unsigned short s[8]; } pk;
#pragma unroll
    for (int e = 0; e < 8; ++e) pk.s[e] = tile[j0 + e][d];
    *(bf16x8*)&vt2[chunk + d * 32 + j0] = pk.v;
}

// ---------- generic A[M,K] * B^T[N,K] bf16 MFMA GEMM ----------
template <int BM, int BN, int BK, bool OUT_BF16, bool HAS_BIAS>
__global__ __launch_bounds__(256) void gemm_bt(
    const unsigned short* __restrict__ A, int ldA, long long sA,
    const unsigned short* __restrict__ B, int ldB, long long sB,
    void* __restrict__ Cv, int ldC, long long sC,
    const float* __restrict__ bias, float scale, int K) {
    constexpr int PAD = 8, LDR = BK + PAD;
    __shared__ __align__(16) unsigned short As[BM * LDR];
    __shared__ __align__(16) unsigned short Bs[BN * LDR];

    const int tid = threadIdx.x;
    const int lane = tid & 63, wv = tid >> 6;
    const int wm = wv >> 1, wn = wv & 1;
    constexpr int WM = BM / 2, WN = BN / 2;
    constexpr int MF = WM / 16, NF = WN / 16;
    constexpr int KG = BK / 8;

    const int m0 = blockIdx.x * BM, n0 = blockIdx.y * BN;
    A += (long long)blockIdx.z * sA;
    B += (long long)blockIdx.z * sB;

    const int lr = lane & 15, lk = (lane >> 4) * 8;

    f32x4 acc[MF][NF];
#pragma unroll
    for (int m = 0; m < MF; ++m)
#pragma unroll
        for (int n = 0; n < NF; ++n) acc[m][n] = (f32x4){0.f, 0.f, 0.f, 0.f};

    for (int k0 = 0; k0 < K; k0 += BK) {
#pragma unroll
        for (int i = 0; i < BM * KG / 256; ++i) {
            int c = i * 256 + tid;
            int row = c / KG, kg = c % KG;
            *(bf16x8*)&As[row * LDR + kg * 8] =
                *(const bf16x8*)&A[(size_t)(m0 + row) * ldA + k0 + kg * 8];
        }
#pragma unroll
        for (int i = 0; i < BN * KG / 256; ++i) {
            int c = i * 256 + tid;
            int row = c / KG, kg = c % KG;
            *(bf16x8*)&Bs[row * LDR + kg * 8] =
                *(const bf16x8*)&B[(size_t)(n0 + row) * ldB + k0 + kg * 8];
        }
        __syncthreads();
#pragma unroll
        for (int kk = 0; kk < BK; kk += 32) {
            bf16x8 af[MF], bfr[NF];
#pragma unroll
            for (int m = 0; m < MF; ++m)
                af[m] = *(const bf16x8*)&As[(wm * WM + m * 16 + lr) * LDR + kk + lk];
#pragma unroll
            for (int n = 0; n < NF; ++n)
                bfr[n] = *(const bf16x8*)&Bs[(wn * WN + n * 16 + lr) * LDR + kk + lk];
#pragma unroll
            for (int m = 0; m < MF; ++m)
#pragma unroll
                for (int n = 0; n < NF; ++n)
                    acc[m][n] = __builtin_amdgcn_mfma_f32_16x16x32_bf16(af[m], bfr[n], acc[m][n], 0, 0, 0);
        }
        __syncthreads();
    }

    const int rb = (lane >> 4) * 4;
    const long long cbase = (long long)blockIdx.z * sC;
#pragma unroll
    for (int m = 0; m < MF; ++m) {
#pragma unroll
        for (int n = 0; n < NF; ++n) {
            int col = n0 + wn * WN + n * 16 + lr;
            float bv = HAS_BIAS ? bias[col] : 0.0f;
#pragma unroll
            for (int r = 0; r < 4; ++r) {
                int row = m0 + wm * WM + m * 16 + rb + r;
                float v = acc[m][n][r] * scale + bv;
                if constexpr (OUT_BF16)
                    ((unsigned short*)Cv)[cbase + (size_t)row * ldC + col] = f2bf(v);
                else
                    ((float*)Cv)[cbase + (size_t)row * ldC + col] = v;
            }
        }
    }
}

#define C_SCALE 0.18033688f

// ---------- pass 1: nllog[b,h,i] = -log2(sum_j exp2(S)) ----------
// grid 1024 = (b, h, it64), 256 thr = 4 waves, no barriers, no LDS.
__global__ __launch_bounds__(256) void k_pass1(
    const unsigned short* __restrict__ qkv,
    const unsigned short* __restrict__ kt2,
    float* __restrict__ nllog) {
    const int blk = blockIdx.x;
    const int b = blk & 7, r = blk >> 3;
    const int h = r & 7, it = r >> 3;   // it 0..15
    const int tid = threadIdx.x;
    const int lane = tid & 63, w = tid >> 6;
    const int lr = lane & 15, qq = lane >> 4;
    const int i0 = it * 64 + w * 16;

    bf16x8 qf[2];
#pragma unroll
    for (int kk = 0; kk < 2; ++kk) {
        bf16x8 raw = *(const bf16x8*)&qkv[(size_t)(b * 1024 + i0 + lr) * 1536 +
                                          h * 64 + kk * 32 + qq * 8];
        union { bf16x8 v; unsigned u[4]; } pk;
#pragma unroll
        for (int e = 0; e < 4; ++e)
            pk.u[e] = cvt_pk_bf16(bf2f((unsigned short)raw[2 * e]) * C_SCALE,
                                  bf2f((unsigned short)raw[2 * e + 1]) * C_SCALE);
        qf[kk] = pk.v;
    }

    const unsigned short* kbase = kt2 + ((size_t)(b * 8 + h)) * 32 * 2048;
    const int kfo0 = lr * 32 + qq * 8;
    const int kfo1 = kfo0 + 512;

    float lacc = 0.f;
    bf16x8 kC0 = *(const bf16x8*)(kbase + kfo0);
    bf16x8 kC1 = *(const bf16x8*)(kbase + 1024 + kfo0);
    bf16x8 kC2 = *(const bf16x8*)(kbase + kfo1);
    bf16x8 kC3 = *(const bf16x8*)(kbase + 1024 + kfo1);
    for (int n = 0; n < 32; ++n) {
        int np = (n + 1) & 31;
        const unsigned short* kch = kbase + (size_t)np * 2048;
        bf16x8 kN0 = *(const bf16x8*)(kch + kfo0);
        bf16x8 kN1 = *(const bf16x8*)(kch + 1024 + kfo0);
        bf16x8 kN2 = *(const bf16x8*)(kch + kfo1);
        bf16x8 kN3 = *(const bf16x8*)(kch + 1024 + kfo1);
        f32x4 a0 = (f32x4){0.f, 0.f, 0.f, 0.f}, a1 = (f32x4){0.f, 0.f, 0.f, 0.f};
        a0 = __builtin_amdgcn_mfma_f32_16x16x32_bf16(kC0, qf[0], a0, 0, 0, 0);
        a0 = __builtin_amdgcn_mfma_f32_16x16x32_bf16(kC1, qf[1], a0, 0, 0, 0);
        a1 = __builtin_amdgcn_mfma_f32_16x16x32_bf16(kC2, qf[0], a1, 0, 0, 0);
        a1 = __builtin_amdgcn_mfma_f32_16x16x32_bf16(kC3, qf[1], a1, 0, 0, 0);
#pragma unroll
        for (int rr = 0; rr < 4; ++rr) lacc += fast_exp2(a0[rr]) + fast_exp2(a1[rr]);
        kC0 = kN0; kC1 = kN1; kC2 = kN2; kC3 = kN3;
    }
    lacc += __shfl_xor(lacc, 16);
    lacc += __shfl_xor(lacc, 32);
    if (qq == 0) nllog[((b * 8 + h) << 10) + i0 + lr] = -__log2f(lacc);
}

// ---------- fused pass 2 (v6 structure): p -> remix(MFMA) -> LN -> PV ----------
// grid 256 (b = blk&7, i-tile32 = blk>>3), 512 thr = 8 waves = 8 heads.
__global__ __launch_bounds__(512) void attn_fused(
    const unsigned short* __restrict__ qkv,   // [8192][1536] bf16
    const unsigned short* __restrict__ kt2,   // tiled K
    const unsigned short* __restrict__ vt2,   // tiled V^T
    const float* __restrict__ nllog,          // -log2(l) per (b,h,i)
    unsigned short* __restrict__ pvout,       // [8192][512] bf16
    const float* __restrict__ Wm,
    const float* __restrict__ ln_g, const float* __restrict__ ln_b) {
    const int blk = blockIdx.x;
    const int b = blk & 7, it = blk >> 3;
    const int i0 = it * 32;
    const int tid = threadIdx.x;
    const int lane = tid & 63, h = tid >> 6;
    const int lr = lane & 15, qq = lane >> 4;

    __shared__ __align__(16) unsigned short Ps[32 * 32 * 8];   // 16 KB [i][jr][h]
    __shared__ __align__(16) unsigned short Rs[8 * 32 * 40];   // 20 KB [g][i][j pad40]
    __shared__ __align__(16) unsigned short Wa[16 * 8];
    __shared__ __align__(16) unsigned short zst[8];

    // Wa[g][hh] = W[hh][g] - mean_g' W[hh][g']  (rows g>=8 zero)
    if (tid < 128) {
        int g = tid >> 3, hh = tid & 7;
        float v = 0.f;
        if (g < 8) {
            float s = 0.f;
#pragma unroll
            for (int g2 = 0; g2 < 8; ++g2) s += Wm[hh * 8 + g2];
            v = Wm[hh * 8 + g] - s * 0.125f;
        }
        Wa[g * 8 + hh] = f2bf(v);
    }
    if (tid < 8) zst[tid] = 0;

    const int hi4 = qq & 1;
    float gm[4], bt[4];
#pragma unroll
    for (int r = 0; r < 4; ++r) {
        gm[r] = ln_g[hi4 * 4 + r];
        bt[r] = ln_b[hi4 * 4 + r];
    }

    // Q fragments (B-operand), prescaled by log2(e)/8
    bf16x8 qf[2][2];
#pragma unroll
    for (int ni = 0; ni < 2; ++ni)
#pragma unroll
        for (int kk = 0; kk < 2; ++kk) {
            bf16x8 raw = *(const bf16x8*)&qkv[(size_t)(b * 1024 + i0 + ni * 16 + lr) * 1536 +
                                              h * 64 + kk * 32 + qq * 8];
            union { bf16x8 v; unsigned u[4]; } pk;
#pragma unroll
            for (int e = 0; e < 4; ++e)
                pk.u[e] = cvt_pk_bf16(bf2f((unsigned short)raw[2 * e]) * C_SCALE,
                                      bf2f((unsigned short)raw[2 * e + 1]) * C_SCALE);
            qf[ni][kk] = pk.v;
        }

    // per-row -log2(l) from pass 1, folded into QK^T accumulator init
    f32x4 cinit[2];
#pragma unroll
    for (int ni = 0; ni < 2; ++ni) {
        float v = nllog[((b * 8 + h) << 10) + i0 + ni * 16 + lr];
        cinit[ni] = (f32x4){v, v, v, v};
    }

    const unsigned short* kbase = kt2 + ((size_t)(b * 8 + h)) * 32 * 2048;
    const unsigned short* vbase = vt2 + ((size_t)(b * 8 + h)) * 32 * 2048;
    const int kfo0 = lr * 32 + qq * 8;
    const int kfo1 = (16 + lr) * 32 + qq * 8;
    const int vfo = lr * 32 + qq * 8;

    __syncthreads();   // Wa/zst visible

    bf16x8 wfrag = *(const bf16x8*)((qq == 0) ? (const void*)&Wa[lr * 8] : (const void*)zst);

    f32x4 o[2][4];
#pragma unroll
    for (int pp = 0; pp < 2; ++pp)
#pragma unroll
        for (int nd = 0; nd < 4; ++nd) o[pp][nd] = (f32x4){0.f, 0.f, 0.f, 0.f};

    // prefetch K chunk 0
    bf16x8 kC0 = *(const bf16x8*)(kbase + kfo0);
    bf16x8 kC1 = *(const bf16x8*)(kbase + 1024 + kfo0);
    bf16x8 kC2 = *(const bf16x8*)(kbase + kfo1);
    bf16x8 kC3 = *(const bf16x8*)(kbase + 1024 + kfo1);

    for (int n = 0; n < 32; ++n) {
        // V(n) frags (coalesced), K(n+1) prefetch (coalesced)
        const unsigned short* vch = vbase + (size_t)n * 2048;
        bf16x8 vf[4];
#pragma unroll
        for (int nd = 0; nd < 4; ++nd)
            vf[nd] = *(const bf16x8*)(vch + nd * 512 + vfo);
        int np = (n + 1) & 31;
        const unsigned short* kch = kbase + (size_t)np * 2048;
        bf16x8 kN0 = *(const bf16x8*)(kch + kfo0);
        bf16x8 kN1 = *(const bf16x8*)(kch + 1024 + kfo0);
        bf16x8 kN2 = *(const bf16x8*)(kch + kfo1);
        bf16x8 kN3 = *(const bf16x8*)(kch + 1024 + kfo1);

        // QK^T with C = -llog: a[.] = S - llog directly
        f32x4 a[2][2];
#pragma unroll
        for (int ni = 0; ni < 2; ++ni) { a[0][ni] = cinit[ni]; a[1][ni] = cinit[ni]; }
#pragma unroll
        for (int ni = 0; ni < 2; ++ni) {
            a[0][ni] = __builtin_amdgcn_mfma_f32_16x16x32_bf16(kC0, qf[ni][0], a[0][ni], 0, 0, 0);
            a[0][ni] = __builtin_amdgcn_mfma_f32_16x16x32_bf16(kC1, qf[ni][1], a[0][ni], 0, 0, 0);
            a[1][ni] = __builtin_amdgcn_mfma_f32_16x16x32_bf16(kC2, qf[ni][0], a[1][ni], 0, 0, 0);
            a[1][ni] = __builtin_amdgcn_mfma_f32_16x16x32_bf16(kC3, qf[ni][1], a[1][ni], 0, 0, 0);
        }

        // p = exp2(a) -> Ps[i][(j+5i)&31][h]
#pragma unroll
        for (int ni = 0; ni < 2; ++ni) {
            const int i = ni * 16 + lr;
            const int ibase = i * 32;
#pragma unroll
            for (int mf = 0; mf < 2; ++mf) {
                const int jb = mf * 16 + qq * 4;
#pragma unroll
                for (int rr = 0; rr < 4; ++rr) {
                    float p = fast_exp2(a[mf][ni][rr]);
                    int jr = (jb + rr + 5 * i) & 31;
                    Ps[(ibase + jr) * 8 + h] = f2bf(p);
                }
            }
        }
        __syncthreads();   // A: Ps complete

        // remix via MFMA: wave h owns ii in {4h..4h+3}, jz in {0,1}
#pragma unroll
        for (int z = 0; z < 8; ++z) {
            const int ii = h * 4 + (z & 3), jz = z >> 2;
            const int jcol = jz * 16 + lr;
            const void* paddr = (qq == 0)
                ? (const void*)&Ps[(ii * 32 + ((jcol + 5 * ii) & 31)) * 8]
                : (const void*)zst;
            bf16x8 pf = *(const bf16x8*)paddr;
            f32x4 d = __builtin_amdgcn_mfma_f32_16x16x32_bf16(wfrag, pf,
                        (f32x4){0.f, 0.f, 0.f, 0.f}, 0, 0, 0);
            float s2 = d[0] * d[0] + d[1] * d[1];
            s2 = fmaf(d[2], d[2], s2);
            s2 = fmaf(d[3], d[3], s2);
            s2 += __shfl_xor(s2, 16);
            float rs = rsqrtf(s2 * 0.125f + 1e-5f);
            if (lane < 32) {
                const int gb = hi4 * 4;
#pragma unroll
                for (int r = 0; r < 4; ++r)
                    Rs[((gb + r) * 32 + ii) * 40 + jcol] =
                        f2bf(d[r] * rs * gm[r] + bt[r]);
            }
        }
        __syncthreads();   // B: Rs complete

        // PV: A = Rs[g=h] (rows i, k = j), B = V^T frags (regs)
#pragma unroll
        for (int pp = 0; pp < 2; ++pp) {
            bf16x8 rf = *(const bf16x8*)&Rs[(h * 32 + pp * 16 + lr) * 40 + qq * 8];
#pragma unroll
            for (int nd = 0; nd < 4; ++nd)
                o[pp][nd] = __builtin_amdgcn_mfma_f32_16x16x32_bf16(rf, vf[nd], o[pp][nd], 0, 0, 0);
        }
        kC0 = kN0; kC1 = kN1; kC2 = kN2; kC3 = kN3;
    }

    // epilogue: D[row i = qq*4+rr][col d = nd*16+lr]
#pragma unroll
    for (int pp = 0; pp < 2; ++pp)
#pragma unroll
        for (int nd = 0; nd < 4; ++nd)
#pragma unroll
            for (int rr = 0; rr < 4; ++rr) {
                int i = i0 + pp * 16 + qq * 4 + rr;
                int d = nd * 16 + lr;
                pvout[(size_t)(b * 1024 + i) * 512 + h * 64 + d] = f2bf(o[pp][nd][rr]);
            }
}

extern "C" void kernel_launch(void* const* d_in, const int* in_sizes, int n_in,
                              void* d_out, int out_size, void* d_ws, size_t ws_size,
                              hipStream_t stream) {
    const float* x        = (const float*)d_in[0];
    const float* w_qkv    = (const float*)d_in[1];
    const float* reattn_w = (const float*)d_in[2];
    const float* ln_g     = (const float*)d_in[3];
    const float* ln_b     = (const float*)d_in[4];
    const float* w_out    = (const float*)d_in[5];
    const float* b_out    = (const float*)d_in[6];
    float* out = (float*)d_out;

    char* ws = (char*)d_ws;
    unsigned short* x_bf  = (unsigned short*)(ws + 0);          //  8 MB
    unsigned short* wqkvT = (unsigned short*)(ws + 8388608);    //  1.5MB
    unsigned short* woutT = (unsigned short*)(ws + 9961472);    //  0.5MB
    unsigned short* qkv   = (unsigned short*)(ws + 10485760);   // 24 MB
    unsigned short* kt2   = (unsigned short*)(ws + 35651584);   //  8 MB
    unsigned short* vt2   = (unsigned short*)(ws + 44040192);   //  8 MB
    unsigned short* pv    = (unsigned short*)(ws + 52428800);   //  8 MB
    float*          nllog = (float*)(ws + 60817408);            // 256 KB

    k_f32_to_bf16<<<4096, 256, 0, stream>>>(x, x_bf, 1048576);
    k_transpose_bf16<<<3072, 256, 0, stream>>>(w_qkv, wqkvT, 512, 1536);
    k_transpose_bf16<<<1024, 256, 0, stream>>>(w_out, woutT, 512, 512);

    // qkv = x @ w_qkv   (M=8192, N=1536, K=512)
    gemm_bt<128, 128, 64, true, false><<<dim3(64, 12, 1), 256, 0, stream>>>(
        x_bf, 512, 0, wqkvT, 512, 0, qkv, 1536, 0, nullptr, 1.0f, 512);

    // K/V fragment-tile relayout
    k_relayout<<<dim3(32, 64), 256, 0, stream>>>(qkv, kt2, vt2);

    // pass 1: softmax denominators (high occupancy, no barriers)
    k_pass1<<<1024, 256, 0, stream>>>(qkv, kt2, nllog);

    // pass 2: fused softmax+remix+LN+PV (v6 structure)
    attn_fused<<<256, 512, 0, stream>>>(qkv, kt2, vt2, nllog, pv, reattn_w, ln_g, ln_b);

    // out = pv @ w_out + b_out   (M=8192, N=512, K=512), fp32 out
    gemm_bt<128, 128, 64, false, true><<<dim3(64, 4, 1), 256, 0, stream>>>(
        pv, 512, 0, woutT, 512, 0, out, 512, 0, b_out, 1.0f, 512);
}

// Round 10
// 152.043 us; speedup vs baseline: 1.1306x; 1.1306x over previous
//
#include <hip/hip_runtime.h>
#include <hip/hip_bf16.h>

typedef short bf16x8 __attribute__((ext_vector_type(8)));
typedef float f32x4 __attribute__((ext_vector_type(4)));

__device__ inline unsigned short f2bf(float f) {
    union { float f; unsigned u; } c; c.f = f;
    unsigned r = c.u + 0x7fffu + ((c.u >> 16) & 1u);
    return (unsigned short)(r >> 16);
}
__device__ inline float bf2f(unsigned short u) {
    union { unsigned u; float f; } c; c.u = ((unsigned)u) << 16; return c.f;
}
__device__ inline unsigned cvt_pk_bf16(float lo, float hi) {
    unsigned r;
    asm("v_cvt_pk_bf16_f32 %0, %1, %2" : "=v"(r) : "v"(lo), "v"(hi));
    return r;
}
__device__ inline float fast_exp2(float x) {
#if __has_builtin(__builtin_amdgcn_exp2f)
    return __builtin_amdgcn_exp2f(x);
#else
    return __exp2f(x);
#endif
}

// ---------- fp32 -> bf16 convert ----------
__global__ __launch_bounds__(256) void k_f32_to_bf16(const float* __restrict__ in,
                                                     unsigned short* __restrict__ out, int n4) {
    int i = blockIdx.x * 256 + threadIdx.x;
    if (i >= n4) return;
    f32x4 v = *(const f32x4*)&in[(size_t)i * 4];
    ushort4 o;
    o.x = f2bf(v[0]); o.y = f2bf(v[1]); o.z = f2bf(v[2]); o.w = f2bf(v[3]);
    *(ushort4*)&out[(size_t)i * 4] = o;
}

// ---------- transpose [K][N] fp32 -> [N][K] bf16 ----------
__global__ __launch_bounds__(256) void k_transpose_bf16(const float* __restrict__ in,
                                                        unsigned short* __restrict__ out,
                                                        int K, int N) {
    int idx = blockIdx.x * 256 + threadIdx.x;
    if (idx >= N * K) return;
    int n = idx / K, k = idx % K;
    out[idx] = f2bf(in[(size_t)k * N + n]);
}

// ---------- re-layout K and V into MFMA-fragment-coalesced tiles ----------
__global__ __launch_bounds__(256) void k_relayout(const unsigned short* __restrict__ qkv,
                                                  unsigned short* __restrict__ kt2,
                                                  unsigned short* __restrict__ vt2) {
    const int bh = blockIdx.y;
    const int b = bh >> 3, h = bh & 7;
    const int jt = blockIdx.x;
    const int t = threadIdx.x;
    __shared__ unsigned short tile[32][72];
    const int j = t >> 3, dc = (t & 7) * 8;
    const size_t qbase = (size_t)(b * 1024 + jt * 32 + j) * 1536;
    const size_t chunk = ((size_t)bh * 32 + jt) * 2048;
    bf16x8 kv = *(const bf16x8*)&qkv[qbase + 512 + h * 64 + dc];
    *(bf16x8*)&kt2[chunk + (dc >> 5) * 1024 + j * 32 + (dc & 31)] = kv;
    bf16x8 vv = *(const bf16x8*)&qkv[qbase + 1024 + h * 64 + dc];
    *(bf16x8*)&tile[j][dc] = vv;
    __syncthreads();
    const int d = t >> 2, j0 = (t & 3) * 8;
    union { bf16x8 v; unsigned short s[8]; } pk;
#pragma unroll
    for (int e = 0; e < 8; ++e) pk.s[e] = tile[j0 + e][d];
    *(bf16x8*)&vt2[chunk + d * 32 + j0] = pk.v;
}

// ---------- generic A[M,K] * B^T[N,K] bf16 MFMA GEMM ----------
template <int BM, int BN, int BK, bool OUT_BF16, bool HAS_BIAS>
__global__ __launch_bounds__(256) void gemm_bt(
    const unsigned short* __restrict__ A, int ldA, long long sA,
    const unsigned short* __restrict__ B, int ldB, long long sB,
    void* __restrict__ Cv, int ldC, long long sC,
    const float* __restrict__ bias, float scale, int K) {
    constexpr int PAD = 8, LDR = BK + PAD;
    __shared__ __align__(16) unsigned short As[BM * LDR];
    __shared__ __align__(16) unsigned short Bs[BN * LDR];

    const int tid = threadIdx.x;
    const int lane = tid & 63, wv = tid >> 6;
    const int wm = wv >> 1, wn = wv & 1;
    constexpr int WM = BM / 2, WN = BN / 2;
    constexpr int MF = WM / 16, NF = WN / 16;
    constexpr int KG = BK / 8;

    const int m0 = blockIdx.x * BM, n0 = blockIdx.y * BN;
    A += (long long)blockIdx.z * sA;
    B += (long long)blockIdx.z * sB;

    const int lr = lane & 15, lk = (lane >> 4) * 8;

    f32x4 acc[MF][NF];
#pragma unroll
    for (int m = 0; m < MF; ++m)
#pragma unroll
        for (int n = 0; n < NF; ++n) acc[m][n] = (f32x4){0.f, 0.f, 0.f, 0.f};

    for (int k0 = 0; k0 < K; k0 += BK) {
#pragma unroll
        for (int i = 0; i < BM * KG / 256; ++i) {
            int c = i * 256 + tid;
            int row = c / KG, kg = c % KG;
            *(bf16x8*)&As[row * LDR + kg * 8] =
                *(const bf16x8*)&A[(size_t)(m0 + row) * ldA + k0 + kg * 8];
        }
#pragma unroll
        for (int i = 0; i < BN * KG / 256; ++i) {
            int c = i * 256 + tid;
            int row = c / KG, kg = c % KG;
            *(bf16x8*)&Bs[row * LDR + kg * 8] =
                *(const bf16x8*)&B[(size_t)(n0 + row) * ldB + k0 + kg * 8];
        }
        __syncthreads();
#pragma unroll
        for (int kk = 0; kk < BK; kk += 32) {
            bf16x8 af[MF], bfr[NF];
#pragma unroll
            for (int m = 0; m < MF; ++m)
                af[m] = *(const bf16x8*)&As[(wm * WM + m * 16 + lr) * LDR + kk + lk];
#pragma unroll
            for (int n = 0; n < NF; ++n)
                bfr[n] = *(const bf16x8*)&Bs[(wn * WN + n * 16 + lr) * LDR + kk + lk];
#pragma unroll
            for (int m = 0; m < MF; ++m)
#pragma unroll
                for (int n = 0; n < NF; ++n)
                    acc[m][n] = __builtin_amdgcn_mfma_f32_16x16x32_bf16(af[m], bfr[n], acc[m][n], 0, 0, 0);
        }
        __syncthreads();
    }

    const int rb = (lane >> 4) * 4;
    const long long cbase = (long long)blockIdx.z * sC;
#pragma unroll
    for (int m = 0; m < MF; ++m) {
#pragma unroll
        for (int n = 0; n < NF; ++n) {
            int col = n0 + wn * WN + n * 16 + lr;
            float bv = HAS_BIAS ? bias[col] : 0.0f;
#pragma unroll
            for (int r = 0; r < 4; ++r) {
                int row = m0 + wm * WM + m * 16 + rb + r;
                float v = acc[m][n][r] * scale + bv;
                if constexpr (OUT_BF16)
                    ((unsigned short*)Cv)[cbase + (size_t)row * ldC + col] = f2bf(v);
                else
                    ((float*)Cv)[cbase + (size_t)row * ldC + col] = v;
            }
        }
    }
}

// ---------- fused attention v10: v6 structure + cvt_pk stores + C-init fold ----------
// grid 256 (b = blk&7 -> XCD-local K/V, i-tile32 = blk>>3), 512 thr = 8 waves = 8 heads.
#define C_SCALE 0.18033688f

__global__ __launch_bounds__(512) void attn_fused(
    const unsigned short* __restrict__ qkv,   // [8192][1536] bf16
    const unsigned short* __restrict__ kt2,   // tiled K
    const unsigned short* __restrict__ vt2,   // tiled V^T
    unsigned short* __restrict__ pvout,       // [8192][512] bf16
    const float* __restrict__ Wm,
    const float* __restrict__ ln_g, const float* __restrict__ ln_b) {
    const int blk = blockIdx.x;
    const int b = blk & 7, it = blk >> 3;
    const int i0 = it * 32;
    const int tid = threadIdx.x;
    const int lane = tid & 63, h = tid >> 6;
    const int lr = lane & 15, qq = lane >> 4;

    __shared__ __align__(16) unsigned short Ps[32 * 32 * 8];   // 16 KB [i][jr][h]
    __shared__ __align__(16) unsigned short Rs[8 * 32 * 40];   // 20 KB [g][i][j pad40]
    __shared__ __align__(16) unsigned short Wa[16 * 8];
    __shared__ __align__(16) unsigned short zst[8];

    // Wa[g][hh] = W[hh][g] - mean_g' W[hh][g']  (rows g>=8 zero)
    if (tid < 128) {
        int g = tid >> 3, hh = tid & 7;
        float v = 0.f;
        if (g < 8) {
            float s = 0.f;
#pragma unroll
            for (int g2 = 0; g2 < 8; ++g2) s += Wm[hh * 8 + g2];
            v = Wm[hh * 8 + g] - s * 0.125f;
        }
        Wa[g * 8 + hh] = f2bf(v);
    }
    if (tid < 8) zst[tid] = 0;

    const int hi4 = qq & 1;
    float gm[4], bt[4];
#pragma unroll
    for (int r = 0; r < 4; ++r) {
        gm[r] = ln_g[hi4 * 4 + r];
        bt[r] = ln_b[hi4 * 4 + r];
    }

    // Q fragments (B-operand), prescaled by log2(e)/8
    bf16x8 qf[2][2];
#pragma unroll
    for (int ni = 0; ni < 2; ++ni)
#pragma unroll
        for (int kk = 0; kk < 2; ++kk) {
            bf16x8 raw = *(const bf16x8*)&qkv[(size_t)(b * 1024 + i0 + ni * 16 + lr) * 1536 +
                                              h * 64 + kk * 32 + qq * 8];
            union { bf16x8 v; unsigned u[4]; } pk;
#pragma unroll
            for (int e = 0; e < 4; ++e)
                pk.u[e] = cvt_pk_bf16(bf2f((unsigned short)raw[2 * e]) * C_SCALE,
                                      bf2f((unsigned short)raw[2 * e + 1]) * C_SCALE);
            qf[ni][kk] = pk.v;
        }

    // per-wave tile bases; fragment offsets (coalesced: lr*64B + qq*16B)
    const unsigned short* kbase = kt2 + ((size_t)(b * 8 + h)) * 32 * 2048;
    const unsigned short* vbase = vt2 + ((size_t)(b * 8 + h)) * 32 * 2048;
    const int kfo0 = lr * 32 + qq * 8;
    const int kfo1 = (16 + lr) * 32 + qq * 8;
    const int vfo = lr * 32 + qq * 8;

    // ---- pass 1: l(i) = sum_j exp2(S), barrier-free, K prefetched ----
    float lacc[2] = {0.f, 0.f};
    bf16x8 kC0 = *(const bf16x8*)(kbase + kfo0);
    bf16x8 kC1 = *(const bf16x8*)(kbase + 1024 + kfo0);
    bf16x8 kC2 = *(const bf16x8*)(kbase + kfo1);
    bf16x8 kC3 = *(const bf16x8*)(kbase + 1024 + kfo1);
    for (int n = 0; n < 32; ++n) {
        int np = (n + 1) & 31;
        const unsigned short* kch = kbase + (size_t)np * 2048;
        bf16x8 kN0 = *(const bf16x8*)(kch + kfo0);
        bf16x8 kN1 = *(const bf16x8*)(kch + 1024 + kfo0);
        bf16x8 kN2 = *(const bf16x8*)(kch + kfo1);
        bf16x8 kN3 = *(const bf16x8*)(kch + 1024 + kfo1);
        f32x4 a[2][2];
#pragma unroll
        for (int mf = 0; mf < 2; ++mf)
#pragma unroll
            for (int ni = 0; ni < 2; ++ni) a[mf][ni] = (f32x4){0.f, 0.f, 0.f, 0.f};
#pragma unroll
        for (int ni = 0; ni < 2; ++ni) {
            a[0][ni] = __builtin_amdgcn_mfma_f32_16x16x32_bf16(kC0, qf[ni][0], a[0][ni], 0, 0, 0);
            a[0][ni] = __builtin_amdgcn_mfma_f32_16x16x32_bf16(kC1, qf[ni][1], a[0][ni], 0, 0, 0);
            a[1][ni] = __builtin_amdgcn_mfma_f32_16x16x32_bf16(kC2, qf[ni][0], a[1][ni], 0, 0, 0);
            a[1][ni] = __builtin_amdgcn_mfma_f32_16x16x32_bf16(kC3, qf[ni][1], a[1][ni], 0, 0, 0);
        }
#pragma unroll
        for (int ni = 0; ni < 2; ++ni)
#pragma unroll
            for (int mf = 0; mf < 2; ++mf)
#pragma unroll
                for (int rr = 0; rr < 4; ++rr) lacc[ni] += fast_exp2(a[mf][ni][rr]);
        kC0 = kN0; kC1 = kN1; kC2 = kN2; kC3 = kN3;
    }
#pragma unroll
    for (int ni = 0; ni < 2; ++ni) {
        lacc[ni] += __shfl_xor(lacc[ni], 16);
        lacc[ni] += __shfl_xor(lacc[ni], 32);
    }
    // -log2(l) folded into pass-2 QK^T accumulator init
    f32x4 cinit[2];
#pragma unroll
    for (int ni = 0; ni < 2; ++ni) {
        float v = -__log2f(lacc[ni]);
        cinit[ni] = (f32x4){v, v, v, v};
    }

    __syncthreads();   // Wa/zst visible

    bf16x8 wfrag = *(const bf16x8*)((qq == 0) ? (const void*)&Wa[lr * 8] : (const void*)zst);

    f32x4 o[2][4];
#pragma unroll
    for (int pp = 0; pp < 2; ++pp)
#pragma unroll
        for (int nd = 0; nd < 4; ++nd) o[pp][nd] = (f32x4){0.f, 0.f, 0.f, 0.f};

    // ---- pass 2 ----
    for (int n = 0; n < 32; ++n) {
        // V(n) frags (coalesced), K(n+1) prefetch (coalesced)
        const unsigned short* vch = vbase + (size_t)n * 2048;
        bf16x8 vf[4];
#pragma unroll
        for (int nd = 0; nd < 4; ++nd)
            vf[nd] = *(const bf16x8*)(vch + nd * 512 + vfo);
        int np = (n + 1) & 31;
        const unsigned short* kch = kbase + (size_t)np * 2048;
        bf16x8 kN0 = *(const bf16x8*)(kch + kfo0);
        bf16x8 kN1 = *(const bf16x8*)(kch + 1024 + kfo0);
        bf16x8 kN2 = *(const bf16x8*)(kch + kfo1);
        bf16x8 kN3 = *(const bf16x8*)(kch + 1024 + kfo1);

        // QK^T with C = -log2(l): a = S - log2(l) directly
        f32x4 a[2][2];
#pragma unroll
        for (int ni = 0; ni < 2; ++ni) { a[0][ni] = cinit[ni]; a[1][ni] = cinit[ni]; }
#pragma unroll
        for (int ni = 0; ni < 2; ++ni) {
            a[0][ni] = __builtin_amdgcn_mfma_f32_16x16x32_bf16(kC0, qf[ni][0], a[0][ni], 0, 0, 0);
            a[0][ni] = __builtin_amdgcn_mfma_f32_16x16x32_bf16(kC1, qf[ni][1], a[0][ni], 0, 0, 0);
            a[1][ni] = __builtin_amdgcn_mfma_f32_16x16x32_bf16(kC2, qf[ni][0], a[1][ni], 0, 0, 0);
            a[1][ni] = __builtin_amdgcn_mfma_f32_16x16x32_bf16(kC3, qf[ni][1], a[1][ni], 0, 0, 0);
        }

        // p = exp2(a) -> Ps[i][(j+5i)&31][h], packed converts (v7-proven form)
#pragma unroll
        for (int ni = 0; ni < 2; ++ni) {
            const int i = ni * 16 + lr;
            const int ibase = i * 32;
            const int rot = 5 * i;
#pragma unroll
            for (int mf = 0; mf < 2; ++mf) {
                f32x4 av = a[mf][ni];
                unsigned u01 = cvt_pk_bf16(fast_exp2(av[0]), fast_exp2(av[1]));
                unsigned u23 = cvt_pk_bf16(fast_exp2(av[2]), fast_exp2(av[3]));
                const int jb = mf * 16 + qq * 4;
                Ps[(ibase + ((jb + 0 + rot) & 31)) * 8 + h] = (unsigned short)u01;
                Ps[(ibase + ((jb + 1 + rot) & 31)) * 8 + h] = (unsigned short)(u01 >> 16);
                Ps[(ibase + ((jb + 2 + rot) & 31)) * 8 + h] = (unsigned short)u23;
                Ps[(ibase + ((jb + 3 + rot) & 31)) * 8 + h] = (unsigned short)(u23 >> 16);
            }
        }
        __syncthreads();   // A: Ps complete

        // remix via MFMA: wave h owns ii in {4h..4h+3}, jz in {0,1}
#pragma unroll
        for (int z = 0; z < 8; ++z) {
            const int ii = h * 4 + (z & 3), jz = z >> 2;
            const int jcol = jz * 16 + lr;
            const void* paddr = (qq == 0)
                ? (const void*)&Ps[(ii * 32 + ((jcol + 5 * ii) & 31)) * 8]
                : (const void*)zst;
            bf16x8 pf = *(const bf16x8*)paddr;
            f32x4 d = __builtin_amdgcn_mfma_f32_16x16x32_bf16(wfrag, pf,
                        (f32x4){0.f, 0.f, 0.f, 0.f}, 0, 0, 0);
            float s2 = d[0] * d[0] + d[1] * d[1];
            s2 = fmaf(d[2], d[2], s2);
            s2 = fmaf(d[3], d[3], s2);
            s2 += __shfl_xor(s2, 16);
            float rs = rsqrtf(s2 * 0.125f + 1e-5f);
            if (lane < 32) {
                const int gb = hi4 * 4;
                unsigned pk0 = cvt_pk_bf16(d[0] * rs * gm[0] + bt[0], d[1] * rs * gm[1] + bt[1]);
                unsigned pk1 = cvt_pk_bf16(d[2] * rs * gm[2] + bt[2], d[3] * rs * gm[3] + bt[3]);
                Rs[((gb + 0) * 32 + ii) * 40 + jcol] = (unsigned short)pk0;
                Rs[((gb + 1) * 32 + ii) * 40 + jcol] = (unsigned short)(pk0 >> 16);
                Rs[((gb + 2) * 32 + ii) * 40 + jcol] = (unsigned short)pk1;
                Rs[((gb + 3) * 32 + ii) * 40 + jcol] = (unsigned short)(pk1 >> 16);
            }
        }
        __syncthreads();   // B: Rs complete

        // PV: A = Rs[g=h] (rows i, k = j), B = V^T frags (regs)
#pragma unroll
        for (int pp = 0; pp < 2; ++pp) {
            bf16x8 rf = *(const bf16x8*)&Rs[(h * 32 + pp * 16 + lr) * 40 + qq * 8];
#pragma unroll
            for (int nd = 0; nd < 4; ++nd)
                o[pp][nd] = __builtin_amdgcn_mfma_f32_16x16x32_bf16(rf, vf[nd], o[pp][nd], 0, 0, 0);
        }
        kC0 = kN0; kC1 = kN1; kC2 = kN2; kC3 = kN3;
    }

    // epilogue: D[row i = qq*4+rr][col d = nd*16+lr]
#pragma unroll
    for (int pp = 0; pp < 2; ++pp)
#pragma unroll
        for (int nd = 0; nd < 4; ++nd)
#pragma unroll
            for (int rr = 0; rr < 4; ++rr) {
                int i = i0 + pp * 16 + qq * 4 + rr;
                int d = nd * 16 + lr;
                pvout[(size_t)(b * 1024 + i) * 512 + h * 64 + d] = f2bf(o[pp][nd][rr]);
            }
}

extern "C" void kernel_launch(void* const* d_in, const int* in_sizes, int n_in,
                              void* d_out, int out_size, void* d_ws, size_t ws_size,
                              hipStream_t stream) {
    const float* x        = (const float*)d_in[0];
    const float* w_qkv    = (const float*)d_in[1];
    const float* reattn_w = (const float*)d_in[2];
    const float* ln_g     = (const float*)d_in[3];
    const float* ln_b     = (const float*)d_in[4];
    const float* w_out    = (const float*)d_in[5];
    const float* b_out    = (const float*)d_in[6];
    float* out = (float*)d_out;

    char* ws = (char*)d_ws;
    unsigned short* x_bf  = (unsigned short*)(ws + 0);          //  8 MB
    unsigned short* wqkvT = (unsigned short*)(ws + 8388608);    //  1.5MB
    unsigned short* woutT = (unsigned short*)(ws + 9961472);    //  0.5MB
    unsigned short* qkv   = (unsigned short*)(ws + 10485760);   // 24 MB
    unsigned short* kt2   = (unsigned short*)(ws + 35651584);   //  8 MB
    unsigned short* vt2   = (unsigned short*)(ws + 44040192);   //  8 MB
    unsigned short* pv    = (unsigned short*)(ws + 52428800);   //  8 MB

    k_f32_to_bf16<<<4096, 256, 0, stream>>>(x, x_bf, 1048576);
    k_transpose_bf16<<<3072, 256, 0, stream>>>(w_qkv, wqkvT, 512, 1536);
    k_transpose_bf16<<<1024, 256, 0, stream>>>(w_out, woutT, 512, 512);

    // qkv = x @ w_qkv   (M=8192, N=1536, K=512)
    gemm_bt<128, 128, 64, true, false><<<dim3(64, 12, 1), 256, 0, stream>>>(
        x_bf, 512, 0, wqkvT, 512, 0, qkv, 1536, 0, nullptr, 1.0f, 512);

    // K/V fragment-tile relayout
    k_relayout<<<dim3(32, 64), 256, 0, stream>>>(qkv, kt2, vt2);

    // fused attention (two-pass in one kernel, cvt_pk stores, C-init fold)
    attn_fused<<<256, 512, 0, stream>>>(qkv, kt2, vt2, pv, reattn_w, ln_g, ln_b);

    // out = pv @ w_out + b_out   (M=8192, N=512, K=512), fp32 out
    gemm_bt<128, 128, 64, false, true><<<dim3(64, 4, 1), 256, 0, stream>>>(
        pv, 512, 0, woutT, 512, 0, out, 512, 0, b_out, 1.0f, 512);
}

// Round 15
// 146.787 us; speedup vs baseline: 1.1710x; 1.0358x over previous
//
#include <hip/hip_runtime.h>
#include <hip/hip_bf16.h>

typedef short bf16x8 __attribute__((ext_vector_type(8)));
typedef float f32x4 __attribute__((ext_vector_type(4)));

__device__ inline unsigned short f2bf(float f) {
    union { float f; unsigned u; } c; c.f = f;
    unsigned r = c.u + 0x7fffu + ((c.u >> 16) & 1u);
    return (unsigned short)(r >> 16);
}
__device__ inline float bf2f(unsigned short u) {
    union { unsigned u; float f; } c; c.u = ((unsigned)u) << 16; return c.f;
}
__device__ inline unsigned cvt_pk_bf16(float lo, float hi) {
    unsigned r;
    asm("v_cvt_pk_bf16_f32 %0, %1, %2" : "=v"(r) : "v"(lo), "v"(hi));
    return r;
}
__device__ inline float fast_exp2(float x) {
#if __has_builtin(__builtin_amdgcn_exp2f)
    return __builtin_amdgcn_exp2f(x);
#else
    return __exp2f(x);
#endif
}

// ---------- merged prep: x f32->bf16, w_qkv^T, w_out^T (one launch) ----------
__global__ __launch_bounds__(256) void k_prep(const float* __restrict__ x,
                                              unsigned short* __restrict__ x_bf,
                                              const float* __restrict__ w_qkv,
                                              unsigned short* __restrict__ wqkvT,
                                              const float* __restrict__ w_out,
                                              unsigned short* __restrict__ woutT) {
    const int blk = blockIdx.x;
    if (blk < 4096) {
        // x: 1048576 vec4 elements
        int i = blk * 256 + threadIdx.x;
        f32x4 v = *(const f32x4*)&x[(size_t)i * 4];
        ushort4 o;
        o.x = f2bf(v[0]); o.y = f2bf(v[1]); o.z = f2bf(v[2]); o.w = f2bf(v[3]);
        *(ushort4*)&x_bf[(size_t)i * 4] = o;
    } else if (blk < 4096 + 3072) {
        // wqkvT[n][k] = w_qkv[k][n], K=512, N=1536 (786432 elems)
        int idx = (blk - 4096) * 256 + threadIdx.x;
        int n = idx / 512, k = idx % 512;
        wqkvT[idx] = f2bf(w_qkv[(size_t)k * 1536 + n]);
    } else {
        // woutT[n][k] = w_out[k][n], K=512, N=512 (262144 elems)
        int idx = (blk - 7168) * 256 + threadIdx.x;
        int n = idx / 512, k = idx % 512;
        woutT[idx] = f2bf(w_out[(size_t)k * 512 + n]);
    }
}

// ---------- re-layout K and V into MFMA-fragment-coalesced tiles ----------
__global__ __launch_bounds__(256) void k_relayout(const unsigned short* __restrict__ qkv,
                                                  unsigned short* __restrict__ kt2,
                                                  unsigned short* __restrict__ vt2) {
    const int bh = blockIdx.y;
    const int b = bh >> 3, h = bh & 7;
    const int jt = blockIdx.x;
    const int t = threadIdx.x;
    __shared__ unsigned short tile[32][72];
    const int j = t >> 3, dc = (t & 7) * 8;
    const size_t qbase = (size_t)(b * 1024 + jt * 32 + j) * 1536;
    const size_t chunk = ((size_t)bh * 32 + jt) * 2048;
    bf16x8 kv = *(const bf16x8*)&qkv[qbase + 512 + h * 64 + dc];
    *(bf16x8*)&kt2[chunk + (dc >> 5) * 1024 + j * 32 + (dc & 31)] = kv;
    bf16x8 vv = *(const bf16x8*)&qkv[qbase + 1024 + h * 64 + dc];
    *(bf16x8*)&tile[j][dc] = vv;
    __syncthreads();
    const int d = t >> 2, j0 = (t & 3) * 8;
    union { bf16x8 v; unsigned short s[8]; } pk;
#pragma unroll
    for (int e = 0; e < 8; ++e) pk.s[e] = tile[j0 + e][d];
    *(bf16x8*)&vt2[chunk + d * 32 + j0] = pk.v;
}

// ---------- generic A[M,K] * B^T[N,K] bf16 MFMA GEMM ----------
template <int BM, int BN, int BK, bool OUT_BF16, bool HAS_BIAS>
__global__ __launch_bounds__(256) void gemm_bt(
    const unsigned short* __restrict__ A, int ldA, long long sA,
    const unsigned short* __restrict__ B, int ldB, long long sB,
    void* __restrict__ Cv, int ldC, long long sC,
    const float* __restrict__ bias, float scale, int K) {
    constexpr int PAD = 8, LDR = BK + PAD;
    __shared__ __align__(16) unsigned short As[BM * LDR];
    __shared__ __align__(16) unsigned short Bs[BN * LDR];

    const int tid = threadIdx.x;
    const int lane = tid & 63, wv = tid >> 6;
    const int wm = wv >> 1, wn = wv & 1;
    constexpr int WM = BM / 2, WN = BN / 2;
    constexpr int MF = WM / 16, NF = WN / 16;
    constexpr int KG = BK / 8;

    const int m0 = blockIdx.x * BM, n0 = blockIdx.y * BN;
    A += (long long)blockIdx.z * sA;
    B += (long long)blockIdx.z * sB;

    const int lr = lane & 15, lk = (lane >> 4) * 8;

    f32x4 acc[MF][NF];
#pragma unroll
    for (int m = 0; m < MF; ++m)
#pragma unroll
        for (int n = 0; n < NF; ++n) acc[m][n] = (f32x4){0.f, 0.f, 0.f, 0.f};

    for (int k0 = 0; k0 < K; k0 += BK) {
#pragma unroll
        for (int i = 0; i < BM * KG / 256; ++i) {
            int c = i * 256 + tid;
            int row = c / KG, kg = c % KG;
            *(bf16x8*)&As[row * LDR + kg * 8] =
                *(const bf16x8*)&A[(size_t)(m0 + row) * ldA + k0 + kg * 8];
        }
#pragma unroll
        for (int i = 0; i < BN * KG / 256; ++i) {
            int c = i * 256 + tid;
            int row = c / KG, kg = c % KG;
            *(bf16x8*)&Bs[row * LDR + kg * 8] =
                *(const bf16x8*)&B[(size_t)(n0 + row) * ldB + k0 + kg * 8];
        }
        __syncthreads();
#pragma unroll
        for (int kk = 0; kk < BK; kk += 32) {
            bf16x8 af[MF], bfr[NF];
#pragma unroll
            for (int m = 0; m < MF; ++m)
                af[m] = *(const bf16x8*)&As[(wm * WM + m * 16 + lr) * LDR + kk + lk];
#pragma unroll
            for (int n = 0; n < NF; ++n)
                bfr[n] = *(const bf16x8*)&Bs[(wn * WN + n * 16 + lr) * LDR + kk + lk];
#pragma unroll
            for (int m = 0; m < MF; ++m)
#pragma unroll
                for (int n = 0; n < NF; ++n)
                    acc[m][n] = __builtin_amdgcn_mfma_f32_16x16x32_bf16(af[m], bfr[n], acc[m][n], 0, 0, 0);
        }
        __syncthreads();
    }

    const int rb = (lane >> 4) * 4;
    const long long cbase = (long long)blockIdx.z * sC;
#pragma unroll
    for (int m = 0; m < MF; ++m) {
#pragma unroll
        for (int n = 0; n < NF; ++n) {
            int col = n0 + wn * WN + n * 16 + lr;
            float bv = HAS_BIAS ? bias[col] : 0.0f;
#pragma unroll
            for (int r = 0; r < 4; ++r) {
                int row = m0 + wm * WM + m * 16 + rb + r;
                float v = acc[m][n][r] * scale + bv;
                if constexpr (OUT_BF16)
                    ((unsigned short*)Cv)[cbase + (size_t)row * ldC + col] = f2bf(v);
                else
                    ((float*)Cv)[cbase + (size_t)row * ldC + col] = v;
            }
        }
    }
}

// ---------- fused attention (v10, proven): two-pass, MFMA remix, cinit fold ----------
// grid 256 (b = blk&7 -> XCD-local K/V, i-tile32 = blk>>3), 512 thr = 8 waves = 8 heads.
#define C_SCALE 0.18033688f

__global__ __launch_bounds__(512) void attn_fused(
    const unsigned short* __restrict__ qkv,   // [8192][1536] bf16
    const unsigned short* __restrict__ kt2,   // tiled K
    const unsigned short* __restrict__ vt2,   // tiled V^T
    unsigned short* __restrict__ pvout,       // [8192][512] bf16
    const float* __restrict__ Wm,
    const float* __restrict__ ln_g, const float* __restrict__ ln_b) {
    const int blk = blockIdx.x;
    const int b = blk & 7, it = blk >> 3;
    const int i0 = it * 32;
    const int tid = threadIdx.x;
    const int lane = tid & 63, h = tid >> 6;
    const int lr = lane & 15, qq = lane >> 4;

    __shared__ __align__(16) unsigned short Ps[32 * 32 * 8];   // 16 KB [i][jr][h]
    __shared__ __align__(16) unsigned short Rs[8 * 32 * 40];   // 20 KB [g][i][j pad40]
    __shared__ __align__(16) unsigned short Wa[16 * 8];
    __shared__ __align__(16) unsigned short zst[8];

    // Wa[g][hh] = W[hh][g] - mean_g' W[hh][g']  (rows g>=8 zero)
    if (tid < 128) {
        int g = tid >> 3, hh = tid & 7;
        float v = 0.f;
        if (g < 8) {
            float s = 0.f;
#pragma unroll
            for (int g2 = 0; g2 < 8; ++g2) s += Wm[hh * 8 + g2];
            v = Wm[hh * 8 + g] - s * 0.125f;
        }
        Wa[g * 8 + hh] = f2bf(v);
    }
    if (tid < 8) zst[tid] = 0;

    const int hi4 = qq & 1;
    float gm[4], bt[4];
#pragma unroll
    for (int r = 0; r < 4; ++r) {
        gm[r] = ln_g[hi4 * 4 + r];
        bt[r] = ln_b[hi4 * 4 + r];
    }

    // Q fragments (B-operand), prescaled by log2(e)/8
    bf16x8 qf[2][2];
#pragma unroll
    for (int ni = 0; ni < 2; ++ni)
#pragma unroll
        for (int kk = 0; kk < 2; ++kk) {
            bf16x8 raw = *(const bf16x8*)&qkv[(size_t)(b * 1024 + i0 + ni * 16 + lr) * 1536 +
                                              h * 64 + kk * 32 + qq * 8];
            union { bf16x8 v; unsigned u[4]; } pk;
#pragma unroll
            for (int e = 0; e < 4; ++e)
                pk.u[e] = cvt_pk_bf16(bf2f((unsigned short)raw[2 * e]) * C_SCALE,
                                      bf2f((unsigned short)raw[2 * e + 1]) * C_SCALE);
            qf[ni][kk] = pk.v;
        }

    // per-wave tile bases; fragment offsets (coalesced: lr*64B + qq*16B)
    const unsigned short* kbase = kt2 + ((size_t)(b * 8 + h)) * 32 * 2048;
    const unsigned short* vbase = vt2 + ((size_t)(b * 8 + h)) * 32 * 2048;
    const int kfo0 = lr * 32 + qq * 8;
    const int kfo1 = (16 + lr) * 32 + qq * 8;
    const int vfo = lr * 32 + qq * 8;

    // ---- pass 1: l(i) = sum_j exp2(S), barrier-free, K prefetched ----
    float lacc[2] = {0.f, 0.f};
    bf16x8 kC0 = *(const bf16x8*)(kbase + kfo0);
    bf16x8 kC1 = *(const bf16x8*)(kbase + 1024 + kfo0);
    bf16x8 kC2 = *(const bf16x8*)(kbase + kfo1);
    bf16x8 kC3 = *(const bf16x8*)(kbase + 1024 + kfo1);
    for (int n = 0; n < 32; ++n) {
        int np = (n + 1) & 31;
        const unsigned short* kch = kbase + (size_t)np * 2048;
        bf16x8 kN0 = *(const bf16x8*)(kch + kfo0);
        bf16x8 kN1 = *(const bf16x8*)(kch + 1024 + kfo0);
        bf16x8 kN2 = *(const bf16x8*)(kch + kfo1);
        bf16x8 kN3 = *(const bf16x8*)(kch + 1024 + kfo1);
        f32x4 a[2][2];
#pragma unroll
        for (int mf = 0; mf < 2; ++mf)
#pragma unroll
            for (int ni = 0; ni < 2; ++ni) a[mf][ni] = (f32x4){0.f, 0.f, 0.f, 0.f};
#pragma unroll
        for (int ni = 0; ni < 2; ++ni) {
            a[0][ni] = __builtin_amdgcn_mfma_f32_16x16x32_bf16(kC0, qf[ni][0], a[0][ni], 0, 0, 0);
            a[0][ni] = __builtin_amdgcn_mfma_f32_16x16x32_bf16(kC1, qf[ni][1], a[0][ni], 0, 0, 0);
            a[1][ni] = __builtin_amdgcn_mfma_f32_16x16x32_bf16(kC2, qf[ni][0], a[1][ni], 0, 0, 0);
            a[1][ni] = __builtin_amdgcn_mfma_f32_16x16x32_bf16(kC3, qf[ni][1], a[1][ni], 0, 0, 0);
        }
#pragma unroll
        for (int ni = 0; ni < 2; ++ni)
#pragma unroll
            for (int mf = 0; mf < 2; ++mf)
#pragma unroll
                for (int rr = 0; rr < 4; ++rr) lacc[ni] += fast_exp2(a[mf][ni][rr]);
        kC0 = kN0; kC1 = kN1; kC2 = kN2; kC3 = kN3;
    }
#pragma unroll
    for (int ni = 0; ni < 2; ++ni) {
        lacc[ni] += __shfl_xor(lacc[ni], 16);
        lacc[ni] += __shfl_xor(lacc[ni], 32);
    }
    // -log2(l) folded into pass-2 QK^T accumulator init
    f32x4 cinit[2];
#pragma unroll
    for (int ni = 0; ni < 2; ++ni) {
        float v = -__log2f(lacc[ni]);
        cinit[ni] = (f32x4){v, v, v, v};
    }

    __syncthreads();   // Wa/zst visible

    bf16x8 wfrag = *(const bf16x8*)((qq == 0) ? (const void*)&Wa[lr * 8] : (const void*)zst);

    f32x4 o[2][4];
#pragma unroll
    for (int pp = 0; pp < 2; ++pp)
#pragma unroll
        for (int nd = 0; nd < 4; ++nd) o[pp][nd] = (f32x4){0.f, 0.f, 0.f, 0.f};

    // ---- pass 2 ----
    for (int n = 0; n < 32; ++n) {
        // V(n) frags (coalesced), K(n+1) prefetch (coalesced)
        const unsigned short* vch = vbase + (size_t)n * 2048;
        bf16x8 vf[4];
#pragma unroll
        for (int nd = 0; nd < 4; ++nd)
            vf[nd] = *(const bf16x8*)(vch + nd * 512 + vfo);
        int np = (n + 1) & 31;
        const unsigned short* kch = kbase + (size_t)np * 2048;
        bf16x8 kN0 = *(const bf16x8*)(kch + kfo0);
        bf16x8 kN1 = *(const bf16x8*)(kch + 1024 + kfo0);
        bf16x8 kN2 = *(const bf16x8*)(kch + kfo1);
        bf16x8 kN3 = *(const bf16x8*)(kch + 1024 + kfo1);

        // QK^T with C = -log2(l): a = S - log2(l) directly
        f32x4 a[2][2];
#pragma unroll
        for (int ni = 0; ni < 2; ++ni) { a[0][ni] = cinit[ni]; a[1][ni] = cinit[ni]; }
#pragma unroll
        for (int ni = 0; ni < 2; ++ni) {
            a[0][ni] = __builtin_amdgcn_mfma_f32_16x16x32_bf16(kC0, qf[ni][0], a[0][ni], 0, 0, 0);
            a[0][ni] = __builtin_amdgcn_mfma_f32_16x16x32_bf16(kC1, qf[ni][1], a[0][ni], 0, 0, 0);
            a[1][ni] = __builtin_amdgcn_mfma_f32_16x16x32_bf16(kC2, qf[ni][0], a[1][ni], 0, 0, 0);
            a[1][ni] = __builtin_amdgcn_mfma_f32_16x16x32_bf16(kC3, qf[ni][1], a[1][ni], 0, 0, 0);
        }

        // p = exp2(a) -> Ps[i][(j+5i)&31][h], packed converts
#pragma unroll
        for (int ni = 0; ni < 2; ++ni) {
            const int i = ni * 16 + lr;
            const int ibase = i * 32;
            const int rot = 5 * i;
#pragma unroll
            for (int mf = 0; mf < 2; ++mf) {
                f32x4 av = a[mf][ni];
                unsigned u01 = cvt_pk_bf16(fast_exp2(av[0]), fast_exp2(av[1]));
                unsigned u23 = cvt_pk_bf16(fast_exp2(av[2]), fast_exp2(av[3]));
                const int jb = mf * 16 + qq * 4;
                Ps[(ibase + ((jb + 0 + rot) & 31)) * 8 + h] = (unsigned short)u01;
                Ps[(ibase + ((jb + 1 + rot) & 31)) * 8 + h] = (unsigned short)(u01 >> 16);
                Ps[(ibase + ((jb + 2 + rot) & 31)) * 8 + h] = (unsigned short)u23;
                Ps[(ibase + ((jb + 3 + rot) & 31)) * 8 + h] = (unsigned short)(u23 >> 16);
            }
        }
        __syncthreads();   // A: Ps complete

        // remix via MFMA: wave h owns ii in {4h..4h+3}, jz in {0,1}  (v10-exact)
#pragma unroll
        for (int z = 0; z < 8; ++z) {
            const int ii = h * 4 + (z & 3), jz = z >> 2;
            const int jcol = jz * 16 + lr;
            const void* paddr = (qq == 0)
                ? (const void*)&Ps[(ii * 32 + ((jcol + 5 * ii) & 31)) * 8]
                : (const void*)zst;
            bf16x8 pf = *(const bf16x8*)paddr;
            f32x4 d = __builtin_amdgcn_mfma_f32_16x16x32_bf16(wfrag, pf,
                        (f32x4){0.f, 0.f, 0.f, 0.f}, 0, 0, 0);
            float s2 = d[0] * d[0] + d[1] * d[1];
            s2 = fmaf(d[2], d[2], s2);
            s2 = fmaf(d[3], d[3], s2);
            s2 += __shfl_xor(s2, 16);
            float rs = rsqrtf(s2 * 0.125f + 1e-5f);
            if (lane < 32) {
                const int gb = hi4 * 4;
                unsigned pk0 = cvt_pk_bf16(d[0] * rs * gm[0] + bt[0], d[1] * rs * gm[1] + bt[1]);
                unsigned pk1 = cvt_pk_bf16(d[2] * rs * gm[2] + bt[2], d[3] * rs * gm[3] + bt[3]);
                Rs[((gb + 0) * 32 + ii) * 40 + jcol] = (unsigned short)pk0;
                Rs[((gb + 1) * 32 + ii) * 40 + jcol] = (unsigned short)(pk0 >> 16);
                Rs[((gb + 2) * 32 + ii) * 40 + jcol] = (unsigned short)pk1;
                Rs[((gb + 3) * 32 + ii) * 40 + jcol] = (unsigned short)(pk1 >> 16);
            }
        }
        __syncthreads();   // B: Rs complete

        // PV: A = Rs[g=h] (rows i, k = j), B = V^T frags (regs)
#pragma unroll
        for (int pp = 0; pp < 2; ++pp) {
            bf16x8 rf = *(const bf16x8*)&Rs[(h * 32 + pp * 16 + lr) * 40 + qq * 8];
#pragma unroll
            for (int nd = 0; nd < 4; ++nd)
                o[pp][nd] = __builtin_amdgcn_mfma_f32_16x16x32_bf16(rf, vf[nd], o[pp][nd], 0, 0, 0);
        }
        kC0 = kN0; kC1 = kN1; kC2 = kN2; kC3 = kN3;
    }

    // epilogue: D[row i = qq*4+rr][col d = nd*16+lr]
#pragma unroll
    for (int pp = 0; pp < 2; ++pp)
#pragma unroll
        for (int nd = 0; nd < 4; ++nd)
#pragma unroll
            for (int rr = 0; rr < 4; ++rr) {
                int i = i0 + pp * 16 + qq * 4 + rr;
                int d = nd * 16 + lr;
                pvout[(size_t)(b * 1024 + i) * 512 + h * 64 + d] = f2bf(o[pp][nd][rr]);
            }
}

extern "C" void kernel_launch(void* const* d_in, const int* in_sizes, int n_in,
                              void* d_out, int out_size, void* d_ws, size_t ws_size,
                              hipStream_t stream) {
    const float* x        = (const float*)d_in[0];
    const float* w_qkv    = (const float*)d_in[1];
    const float* reattn_w = (const float*)d_in[2];
    const float* ln_g     = (const float*)d_in[3];
    const float* ln_b     = (const float*)d_in[4];
    const float* w_out    = (const float*)d_in[5];
    const float* b_out    = (const float*)d_in[6];
    float* out = (float*)d_out;

    char* ws = (char*)d_ws;
    unsigned short* x_bf  = (unsigned short*)(ws + 0);          //  8 MB
    unsigned short* wqkvT = (unsigned short*)(ws + 8388608);    //  1.5MB
    unsigned short* woutT = (unsigned short*)(ws + 9961472);    //  0.5MB
    unsigned short* qkv   = (unsigned short*)(ws + 10485760);   // 24 MB
    unsigned short* kt2   = (unsigned short*)(ws + 35651584);   //  8 MB
    unsigned short* vt2   = (unsigned short*)(ws + 44040192);   //  8 MB
    unsigned short* pv    = (unsigned short*)(ws + 52428800);   //  8 MB

    // merged prep (convert + both weight transposes)
    k_prep<<<8192, 256, 0, stream>>>(x, x_bf, w_qkv, wqkvT, w_out, woutT);

    // qkv = x @ w_qkv   (M=8192, N=1536, K=512)
    gemm_bt<128, 128, 64, true, false><<<dim3(64, 12, 1), 256, 0, stream>>>(
        x_bf, 512, 0, wqkvT, 512, 0, qkv, 1536, 0, nullptr, 1.0f, 512);

    // K/V fragment-tile relayout
    k_relayout<<<dim3(32, 64), 256, 0, stream>>>(qkv, kt2, vt2);

    // fused attention (v10, proven)
    attn_fused<<<256, 512, 0, stream>>>(qkv, kt2, vt2, pv, reattn_w, ln_g, ln_b);

    // out = pv @ w_out + b_out   (M=8192, N=512, K=512), fp32 out
    gemm_bt<128, 128, 64, false, true><<<dim3(64, 4, 1), 256, 0, stream>>>(
        pv, 512, 0, woutT, 512, 0, out, 512, 0, b_out, 1.0f, 512);
}

// Round 16
// 146.759 us; speedup vs baseline: 1.1713x; 1.0002x over previous
//
#include <hip/hip_runtime.h>
#include <hip/hip_bf16.h>

typedef short bf16x8 __attribute__((ext_vector_type(8)));
typedef float f32x4 __attribute__((ext_vector_type(4)));

__device__ inline unsigned short f2bf(float f) {
    union { float f; unsigned u; } c; c.f = f;
    unsigned r = c.u + 0x7fffu + ((c.u >> 16) & 1u);
    return (unsigned short)(r >> 16);
}
__device__ inline float bf2f(unsigned short u) {
    union { unsigned u; float f; } c; c.u = ((unsigned)u) << 16; return c.f;
}
__device__ inline unsigned cvt_pk_bf16(float lo, float hi) {
    unsigned r;
    asm("v_cvt_pk_bf16_f32 %0, %1, %2" : "=v"(r) : "v"(lo), "v"(hi));
    return r;
}
__device__ inline float fast_exp2(float x) {
#if __has_builtin(__builtin_amdgcn_exp2f)
    return __builtin_amdgcn_exp2f(x);
#else
    return __exp2f(x);
#endif
}

// ---------- merged prep: x f32->bf16, w_qkv^T, w_out^T (one launch) ----------
__global__ __launch_bounds__(256) void k_prep(const float* __restrict__ x,
                                              unsigned short* __restrict__ x_bf,
                                              const float* __restrict__ w_qkv,
                                              unsigned short* __restrict__ wqkvT,
                                              const float* __restrict__ w_out,
                                              unsigned short* __restrict__ woutT) {
    const int blk = blockIdx.x;
    if (blk < 4096) {
        // x: 1048576 vec4 elements
        int i = blk * 256 + threadIdx.x;
        f32x4 v = *(const f32x4*)&x[(size_t)i * 4];
        ushort4 o;
        o.x = f2bf(v[0]); o.y = f2bf(v[1]); o.z = f2bf(v[2]); o.w = f2bf(v[3]);
        *(ushort4*)&x_bf[(size_t)i * 4] = o;
    } else if (blk < 4096 + 3072) {
        // wqkvT[n][k] = w_qkv[k][n], K=512, N=1536 (786432 elems)
        int idx = (blk - 4096) * 256 + threadIdx.x;
        int n = idx / 512, k = idx % 512;
        wqkvT[idx] = f2bf(w_qkv[(size_t)k * 1536 + n]);
    } else {
        // woutT[n][k] = w_out[k][n], K=512, N=512 (262144 elems)
        int idx = (blk - 7168) * 256 + threadIdx.x;
        int n = idx / 512, k = idx % 512;
        woutT[idx] = f2bf(w_out[(size_t)k * 512 + n]);
    }
}

// ---------- re-layout K and V into MFMA-fragment-coalesced tiles ----------
__global__ __launch_bounds__(256) void k_relayout(const unsigned short* __restrict__ qkv,
                                                  unsigned short* __restrict__ kt2,
                                                  unsigned short* __restrict__ vt2) {
    const int bh = blockIdx.y;
    const int b = bh >> 3, h = bh & 7;
    const int jt = blockIdx.x;
    const int t = threadIdx.x;
    __shared__ unsigned short tile[32][72];
    const int j = t >> 3, dc = (t & 7) * 8;
    const size_t qbase = (size_t)(b * 1024 + jt * 32 + j) * 1536;
    const size_t chunk = ((size_t)bh * 32 + jt) * 2048;
    bf16x8 kv = *(const bf16x8*)&qkv[qbase + 512 + h * 64 + dc];
    *(bf16x8*)&kt2[chunk + (dc >> 5) * 1024 + j * 32 + (dc & 31)] = kv;
    bf16x8 vv = *(const bf16x8*)&qkv[qbase + 1024 + h * 64 + dc];
    *(bf16x8*)&tile[j][dc] = vv;
    __syncthreads();
    const int d = t >> 2, j0 = (t & 3) * 8;
    union { bf16x8 v; unsigned short s[8]; } pk;
#pragma unroll
    for (int e = 0; e < 8; ++e) pk.s[e] = tile[j0 + e][d];
    *(bf16x8*)&vt2[chunk + d * 32 + j0] = pk.v;
}

// ---------- generic A[M,K] * B^T[N,K] bf16 MFMA GEMM ----------
template <int BM, int BN, int BK, bool OUT_BF16, bool HAS_BIAS>
__global__ __launch_bounds__(256) void gemm_bt(
    const unsigned short* __restrict__ A, int ldA, long long sA,
    const unsigned short* __restrict__ B, int ldB, long long sB,
    void* __restrict__ Cv, int ldC, long long sC,
    const float* __restrict__ bias, float scale, int K) {
    constexpr int PAD = 8, LDR = BK + PAD;
    __shared__ __align__(16) unsigned short As[BM * LDR];
    __shared__ __align__(16) unsigned short Bs[BN * LDR];

    const int tid = threadIdx.x;
    const int lane = tid & 63, wv = tid >> 6;
    const int wm = wv >> 1, wn = wv & 1;
    constexpr int WM = BM / 2, WN = BN / 2;
    constexpr int MF = WM / 16, NF = WN / 16;
    constexpr int KG = BK / 8;

    const int m0 = blockIdx.x * BM, n0 = blockIdx.y * BN;
    A += (long long)blockIdx.z * sA;
    B += (long long)blockIdx.z * sB;

    const int lr = lane & 15, lk = (lane >> 4) * 8;

    f32x4 acc[MF][NF];
#pragma unroll
    for (int m = 0; m < MF; ++m)
#pragma unroll
        for (int n = 0; n < NF; ++n) acc[m][n] = (f32x4){0.f, 0.f, 0.f, 0.f};

    for (int k0 = 0; k0 < K; k0 += BK) {
#pragma unroll
        for (int i = 0; i < BM * KG / 256; ++i) {
            int c = i * 256 + tid;
            int row = c / KG, kg = c % KG;
            *(bf16x8*)&As[row * LDR + kg * 8] =
                *(const bf16x8*)&A[(size_t)(m0 + row) * ldA + k0 + kg * 8];
        }
#pragma unroll
        for (int i = 0; i < BN * KG / 256; ++i) {
            int c = i * 256 + tid;
            int row = c / KG, kg = c % KG;
            *(bf16x8*)&Bs[row * LDR + kg * 8] =
                *(const bf16x8*)&B[(size_t)(n0 + row) * ldB + k0 + kg * 8];
        }
        __syncthreads();
#pragma unroll
        for (int kk = 0; kk < BK; kk += 32) {
            bf16x8 af[MF], bfr[NF];
#pragma unroll
            for (int m = 0; m < MF; ++m)
                af[m] = *(const bf16x8*)&As[(wm * WM + m * 16 + lr) * LDR + kk + lk];
#pragma unroll
            for (int n = 0; n < NF; ++n)
                bfr[n] = *(const bf16x8*)&Bs[(wn * WN + n * 16 + lr) * LDR + kk + lk];
#pragma unroll
            for (int m = 0; m < MF; ++m)
#pragma unroll
                for (int n = 0; n < NF; ++n)
                    acc[m][n] = __builtin_amdgcn_mfma_f32_16x16x32_bf16(af[m], bfr[n], acc[m][n], 0, 0, 0);
        }
        __syncthreads();
    }

    const int rb = (lane >> 4) * 4;
    const long long cbase = (long long)blockIdx.z * sC;
#pragma unroll
    for (int m = 0; m < MF; ++m) {
#pragma unroll
        for (int n = 0; n < NF; ++n) {
            int col = n0 + wn * WN + n * 16 + lr;
            float bv = HAS_BIAS ? bias[col] : 0.0f;
#pragma unroll
            for (int r = 0; r < 4; ++r) {
                int row = m0 + wm * WM + m * 16 + rb + r;
                float v = acc[m][n][r] * scale + bv;
                if constexpr (OUT_BF16)
                    ((unsigned short*)Cv)[cbase + (size_t)row * ldC + col] = f2bf(v);
                else
                    ((float*)Cv)[cbase + (size_t)row * ldC + col] = v;
            }
        }
    }
}

// ---------- fused attention (v10, proven): two-pass, MFMA remix, cinit fold ----------
// grid 256 (b = blk&7 -> XCD-local K/V, i-tile32 = blk>>3), 512 thr = 8 waves = 8 heads.
#define C_SCALE 0.18033688f

__global__ __launch_bounds__(512) void attn_fused(
    const unsigned short* __restrict__ qkv,   // [8192][1536] bf16
    const unsigned short* __restrict__ kt2,   // tiled K
    const unsigned short* __restrict__ vt2,   // tiled V^T
    unsigned short* __restrict__ pvout,       // [8192][512] bf16
    const float* __restrict__ Wm,
    const float* __restrict__ ln_g, const float* __restrict__ ln_b) {
    const int blk = blockIdx.x;
    const int b = blk & 7, it = blk >> 3;
    const int i0 = it * 32;
    const int tid = threadIdx.x;
    const int lane = tid & 63, h = tid >> 6;
    const int lr = lane & 15, qq = lane >> 4;

    __shared__ __align__(16) unsigned short Ps[32 * 32 * 8];   // 16 KB [i][jr][h]
    __shared__ __align__(16) unsigned short Rs[8 * 32 * 40];   // 20 KB [g][i][j pad40]
    __shared__ __align__(16) unsigned short Wa[16 * 8];
    __shared__ __align__(16) unsigned short zst[8];

    // Wa[g][hh] = W[hh][g] - mean_g' W[hh][g']  (rows g>=8 zero)
    if (tid < 128) {
        int g = tid >> 3, hh = tid & 7;
        float v = 0.f;
        if (g < 8) {
            float s = 0.f;
#pragma unroll
            for (int g2 = 0; g2 < 8; ++g2) s += Wm[hh * 8 + g2];
            v = Wm[hh * 8 + g] - s * 0.125f;
        }
        Wa[g * 8 + hh] = f2bf(v);
    }
    if (tid < 8) zst[tid] = 0;

    const int hi4 = qq & 1;
    float gm[4], bt[4];
#pragma unroll
    for (int r = 0; r < 4; ++r) {
        gm[r] = ln_g[hi4 * 4 + r];
        bt[r] = ln_b[hi4 * 4 + r];
    }

    // Q fragments (B-operand), prescaled by log2(e)/8
    bf16x8 qf[2][2];
#pragma unroll
    for (int ni = 0; ni < 2; ++ni)
#pragma unroll
        for (int kk = 0; kk < 2; ++kk) {
            bf16x8 raw = *(const bf16x8*)&qkv[(size_t)(b * 1024 + i0 + ni * 16 + lr) * 1536 +
                                              h * 64 + kk * 32 + qq * 8];
            union { bf16x8 v; unsigned u[4]; } pk;
#pragma unroll
            for (int e = 0; e < 4; ++e)
                pk.u[e] = cvt_pk_bf16(bf2f((unsigned short)raw[2 * e]) * C_SCALE,
                                      bf2f((unsigned short)raw[2 * e + 1]) * C_SCALE);
            qf[ni][kk] = pk.v;
        }

    // per-wave tile bases; fragment offsets (coalesced: lr*64B + qq*16B)
    const unsigned short* kbase = kt2 + ((size_t)(b * 8 + h)) * 32 * 2048;
    const unsigned short* vbase = vt2 + ((size_t)(b * 8 + h)) * 32 * 2048;
    const int kfo0 = lr * 32 + qq * 8;
    const int kfo1 = (16 + lr) * 32 + qq * 8;
    const int vfo = lr * 32 + qq * 8;

    // ---- pass 1: l(i) = sum_j exp2(S), barrier-free, K prefetched ----
    float lacc[2] = {0.f, 0.f};
    bf16x8 kC0 = *(const bf16x8*)(kbase + kfo0);
    bf16x8 kC1 = *(const bf16x8*)(kbase + 1024 + kfo0);
    bf16x8 kC2 = *(const bf16x8*)(kbase + kfo1);
    bf16x8 kC3 = *(const bf16x8*)(kbase + 1024 + kfo1);
    for (int n = 0; n < 32; ++n) {
        int np = (n + 1) & 31;
        const unsigned short* kch = kbase + (size_t)np * 2048;
        bf16x8 kN0 = *(const bf16x8*)(kch + kfo0);
        bf16x8 kN1 = *(const bf16x8*)(kch + 1024 + kfo0);
        bf16x8 kN2 = *(const bf16x8*)(kch + kfo1);
        bf16x8 kN3 = *(const bf16x8*)(kch + 1024 + kfo1);
        f32x4 a[2][2];
#pragma unroll
        for (int mf = 0; mf < 2; ++mf)
#pragma unroll
            for (int ni = 0; ni < 2; ++ni) a[mf][ni] = (f32x4){0.f, 0.f, 0.f, 0.f};
#pragma unroll
        for (int ni = 0; ni < 2; ++ni) {
            a[0][ni] = __builtin_amdgcn_mfma_f32_16x16x32_bf16(kC0, qf[ni][0], a[0][ni], 0, 0, 0);
            a[0][ni] = __builtin_amdgcn_mfma_f32_16x16x32_bf16(kC1, qf[ni][1], a[0][ni], 0, 0, 0);
            a[1][ni] = __builtin_amdgcn_mfma_f32_16x16x32_bf16(kC2, qf[ni][0], a[1][ni], 0, 0, 0);
            a[1][ni] = __builtin_amdgcn_mfma_f32_16x16x32_bf16(kC3, qf[ni][1], a[1][ni], 0, 0, 0);
        }
#pragma unroll
        for (int ni = 0; ni < 2; ++ni)
#pragma unroll
            for (int mf = 0; mf < 2; ++mf)
#pragma unroll
                for (int rr = 0; rr < 4; ++rr) lacc[ni] += fast_exp2(a[mf][ni][rr]);
        kC0 = kN0; kC1 = kN1; kC2 = kN2; kC3 = kN3;
    }
#pragma unroll
    for (int ni = 0; ni < 2; ++ni) {
        lacc[ni] += __shfl_xor(lacc[ni], 16);
        lacc[ni] += __shfl_xor(lacc[ni], 32);
    }
    // -log2(l) folded into pass-2 QK^T accumulator init
    f32x4 cinit[2];
#pragma unroll
    for (int ni = 0; ni < 2; ++ni) {
        float v = -__log2f(lacc[ni]);
        cinit[ni] = (f32x4){v, v, v, v};
    }

    __syncthreads();   // Wa/zst visible

    bf16x8 wfrag = *(const bf16x8*)((qq == 0) ? (const void*)&Wa[lr * 8] : (const void*)zst);

    f32x4 o[2][4];
#pragma unroll
    for (int pp = 0; pp < 2; ++pp)
#pragma unroll
        for (int nd = 0; nd < 4; ++nd) o[pp][nd] = (f32x4){0.f, 0.f, 0.f, 0.f};

    // ---- pass 2 ----
    for (int n = 0; n < 32; ++n) {
        // V(n) frags (coalesced), K(n+1) prefetch (coalesced)
        const unsigned short* vch = vbase + (size_t)n * 2048;
        bf16x8 vf[4];
#pragma unroll
        for (int nd = 0; nd < 4; ++nd)
            vf[nd] = *(const bf16x8*)(vch + nd * 512 + vfo);
        int np = (n + 1) & 31;
        const unsigned short* kch = kbase + (size_t)np * 2048;
        bf16x8 kN0 = *(const bf16x8*)(kch + kfo0);
        bf16x8 kN1 = *(const bf16x8*)(kch + 1024 + kfo0);
        bf16x8 kN2 = *(const bf16x8*)(kch + kfo1);
        bf16x8 kN3 = *(const bf16x8*)(kch + 1024 + kfo1);

        // QK^T with C = -log2(l): a = S - log2(l) directly
        f32x4 a[2][2];
#pragma unroll
        for (int ni = 0; ni < 2; ++ni) { a[0][ni] = cinit[ni]; a[1][ni] = cinit[ni]; }
#pragma unroll
        for (int ni = 0; ni < 2; ++ni) {
            a[0][ni] = __builtin_amdgcn_mfma_f32_16x16x32_bf16(kC0, qf[ni][0], a[0][ni], 0, 0, 0);
            a[0][ni] = __builtin_amdgcn_mfma_f32_16x16x32_bf16(kC1, qf[ni][1], a[0][ni], 0, 0, 0);
            a[1][ni] = __builtin_amdgcn_mfma_f32_16x16x32_bf16(kC2, qf[ni][0], a[1][ni], 0, 0, 0);
            a[1][ni] = __builtin_amdgcn_mfma_f32_16x16x32_bf16(kC3, qf[ni][1], a[1][ni], 0, 0, 0);
        }

        // p = exp2(a) -> Ps[i][(j+5i)&31][h], packed converts
#pragma unroll
        for (int ni = 0; ni < 2; ++ni) {
            const int i = ni * 16 + lr;
            const int ibase = i * 32;
            const int rot = 5 * i;
#pragma unroll
            for (int mf = 0; mf < 2; ++mf) {
                f32x4 av = a[mf][ni];
                unsigned u01 = cvt_pk_bf16(fast_exp2(av[0]), fast_exp2(av[1]));
                unsigned u23 = cvt_pk_bf16(fast_exp2(av[2]), fast_exp2(av[3]));
                const int jb = mf * 16 + qq * 4;
                Ps[(ibase + ((jb + 0 + rot) & 31)) * 8 + h] = (unsigned short)u01;
                Ps[(ibase + ((jb + 1 + rot) & 31)) * 8 + h] = (unsigned short)(u01 >> 16);
                Ps[(ibase + ((jb + 2 + rot) & 31)) * 8 + h] = (unsigned short)u23;
                Ps[(ibase + ((jb + 3 + rot) & 31)) * 8 + h] = (unsigned short)(u23 >> 16);
            }
        }
        __syncthreads();   // A: Ps complete

        // remix via MFMA: wave h owns ii in {4h..4h+3}, jz in {0,1}  (v10-exact)
#pragma unroll
        for (int z = 0; z < 8; ++z) {
            const int ii = h * 4 + (z & 3), jz = z >> 2;
            const int jcol = jz * 16 + lr;
            const void* paddr = (qq == 0)
                ? (const void*)&Ps[(ii * 32 + ((jcol + 5 * ii) & 31)) * 8]
                : (const void*)zst;
            bf16x8 pf = *(const bf16x8*)paddr;
            f32x4 d = __builtin_amdgcn_mfma_f32_16x16x32_bf16(wfrag, pf,
                        (f32x4){0.f, 0.f, 0.f, 0.f}, 0, 0, 0);
            float s2 = d[0] * d[0] + d[1] * d[1];
            s2 = fmaf(d[2], d[2], s2);
            s2 = fmaf(d[3], d[3], s2);
            s2 += __shfl_xor(s2, 16);
            float rs = rsqrtf(s2 * 0.125f + 1e-5f);
            if (lane < 32) {
                const int gb = hi4 * 4;
                unsigned pk0 = cvt_pk_bf16(d[0] * rs * gm[0] + bt[0], d[1] * rs * gm[1] + bt[1]);
                unsigned pk1 = cvt_pk_bf16(d[2] * rs * gm[2] + bt[2], d[3] * rs * gm[3] + bt[3]);
                Rs[((gb + 0) * 32 + ii) * 40 + jcol] = (unsigned short)pk0;
                Rs[((gb + 1) * 32 + ii) * 40 + jcol] = (unsigned short)(pk0 >> 16);
                Rs[((gb + 2) * 32 + ii) * 40 + jcol] = (unsigned short)pk1;
                Rs[((gb + 3) * 32 + ii) * 40 + jcol] = (unsigned short)(pk1 >> 16);
            }
        }
        __syncthreads();   // B: Rs complete

        // PV: A = Rs[g=h] (rows i, k = j), B = V^T frags (regs)
#pragma unroll
        for (int pp = 0; pp < 2; ++pp) {
            bf16x8 rf = *(const bf16x8*)&Rs[(h * 32 + pp * 16 + lr) * 40 + qq * 8];
#pragma unroll
            for (int nd = 0; nd < 4; ++nd)
                o[pp][nd] = __builtin_amdgcn_mfma_f32_16x16x32_bf16(rf, vf[nd], o[pp][nd], 0, 0, 0);
        }
        kC0 = kN0; kC1 = kN1; kC2 = kN2; kC3 = kN3;
    }

    // epilogue: D[row i = qq*4+rr][col d = nd*16+lr]
#pragma unroll
    for (int pp = 0; pp < 2; ++pp)
#pragma unroll
        for (int nd = 0; nd < 4; ++nd)
#pragma unroll
            for (int rr = 0; rr < 4; ++rr) {
                int i = i0 + pp * 16 + qq * 4 + rr;
                int d = nd * 16 + lr;
                pvout[(size_t)(b * 1024 + i) * 512 + h * 64 + d] = f2bf(o[pp][nd][rr]);
            }
}

extern "C" void kernel_launch(void* const* d_in, const int* in_sizes, int n_in,
                              void* d_out, int out_size, void* d_ws, size_t ws_size,
                              hipStream_t stream) {
    const float* x        = (const float*)d_in[0];
    const float* w_qkv    = (const float*)d_in[1];
    const float* reattn_w = (const float*)d_in[2];
    const float* ln_g     = (const float*)d_in[3];
    const float* ln_b     = (const float*)d_in[4];
    const float* w_out    = (const float*)d_in[5];
    const float* b_out    = (const float*)d_in[6];
    float* out = (float*)d_out;

    char* ws = (char*)d_ws;
    unsigned short* x_bf  = (unsigned short*)(ws + 0);          //  8 MB
    unsigned short* wqkvT = (unsigned short*)(ws + 8388608);    //  1.5MB
    unsigned short* woutT = (unsigned short*)(ws + 9961472);    //  0.5MB
    unsigned short* qkv   = (unsigned short*)(ws + 10485760);   // 24 MB
    unsigned short* kt2   = (unsigned short*)(ws + 35651584);   //  8 MB
    unsigned short* vt2   = (unsigned short*)(ws + 44040192);   //  8 MB
    unsigned short* pv    = (unsigned short*)(ws + 52428800);   //  8 MB

    // merged prep (convert + both weight transposes)
    k_prep<<<8192, 256, 0, stream>>>(x, x_bf, w_qkv, wqkvT, w_out, woutT);

    // qkv = x @ w_qkv   (M=8192, N=1536, K=512)
    gemm_bt<128, 128, 64, true, false><<<dim3(64, 12, 1), 256, 0, stream>>>(
        x_bf, 512, 0, wqkvT, 512, 0, qkv, 1536, 0, nullptr, 1.0f, 512);

    // K/V fragment-tile relayout
    k_relayout<<<dim3(32, 64), 256, 0, stream>>>(qkv, kt2, vt2);

    // fused attention (v10, proven)
    attn_fused<<<256, 512, 0, stream>>>(qkv, kt2, vt2, pv, reattn_w, ln_g, ln_b);

    // out = pv @ w_out + b_out   (M=8192, N=512, K=512), fp32 out
    gemm_bt<128, 128, 64, false, true><<<dim3(64, 4, 1), 256, 0, stream>>>(
        pv, 512, 0, woutT, 512, 0, out, 512, 0, b_out, 1.0f, 512);
}